// Round 14
// baseline (133.974 us; speedup 1.0000x reference)
//
#include <hip/hip_runtime.h>
#include <math.h>

#pragma clang fp contract(off)

// Problem constants
#define CCH   192              // B*c channels; one block per channel
#define HW    (512*512)
#define RNUM  8
#define THREADS 512
#define X4_PER_CH (HW / 4)     // 65536 f32x4 per channel
#define PT    (X4_PER_CH / THREADS) // 128 f32x4 per thread
#define NREG  48               // held in registers (192 VGPRs, pinned)
#define NLDS  14               // held in LDS (114688 B, thread-private slots)
#define NUNH  (PT - NREG - NLDS) // 66 unheld -> re-read (L3-resident tail)

typedef float f32x4 __attribute__((ext_vector_type(4)));

// ---------------------------------------------------------------------------
// Un-contractible fp32 RN ops (HIP's __f*_rn are contractable; default
// -ffp-contract fused mul+add in round 1 -> region flips). absmax==0.0
// confirmed rounds 4-13 with these.
// ---------------------------------------------------------------------------
__device__ __forceinline__ float mul_rn(float a, float b) {
    float r; asm volatile("v_mul_f32 %0, %1, %2" : "=v"(r) : "v"(a), "v"(b)); return r;
}
__device__ __forceinline__ float add_rn(float a, float b) {
    float r; asm volatile("v_add_f32 %0, %1, %2" : "=v"(r) : "v"(a), "v"(b)); return r;
}
__device__ __forceinline__ float sub_rn(float a, float b) {
    float r; asm volatile("v_sub_f32 %0, %1, %2" : "=v"(r) : "v"(a), "v"(b)); return r;
}

// region-value select: id = count(b_i <= v) -> BST, 7 v_cmp + 7 v_cndmask.
__device__ __forceinline__ float bst_sel(float v,
    float b0, float b1, float b2, float b3, float b4, float b5, float b6,
    float r0, float r1, float r2, float r3, float r4, float r5, float r6, float r7) {
    return (v < b3) ? ((v < b1) ? ((v < b0) ? r0 : r1)
                                : ((v < b2) ? r2 : r3))
                    : ((v < b5) ? ((v < b4) ? r4 : r5)
                                : ((v < b6) ? r6 : r7));
}

// ---------------------------------------------------------------------------
// ONE BLOCK = ONE CHANNEL. 192 blocks x 512 threads, 1 block/CU.
// min/max is block-local -> the ONLY sync is __syncthreads(). No atomics,
// no spin, no ws, no cross-block anything (rounds 8-13's residual stalls
// were all in the cross-block sync machinery).
// Per-thread slab PT=128 f32x4: 48 held in regs (budget 256/thread at
// 8 waves/CU via __launch_bounds__(512,2)) + 14 held in LDS + 66 unheld.
// Phase-1 order: regs, LDS, unheld LAST (newest L3 lines); phase-2 order:
// unheld FIRST (L3-resident re-read ~104 MB), then LDS, then regs.
// NT stores: the 197 MB write stream doesn't allocate/evict in L3.
// ---------------------------------------------------------------------------
__global__ __launch_bounds__(THREADS, 2) void k_fused(
        const float* __restrict__ xg,
        const float* __restrict__ region_percentiles,
        const float* __restrict__ proxy_percentiles,
        float* __restrict__ outg) {
    const int tid  = threadIdx.x;
    const int chan = blockIdx.x;

    const f32x4* px = (const f32x4*)xg + (size_t)chan * X4_PER_CH;
    f32x4*       po = (f32x4*)outg     + (size_t)chan * X4_PER_CH;

    __shared__ f32x4 slds[NLDS * THREADS];   // 114688 B, thread-private slots
    __shared__ float smn[THREADS], smx[THREADS];
    __shared__ float sprm[16];

    // ---- phase 1: load once, reduce min/max ----
    float hx[NREG], hy[NREG], hz[NREG], hw[NREG];
    float mn = INFINITY, mx = -INFINITY;
    #pragma unroll
    for (int k = 0; k < NREG; ++k) {
        const f32x4 t = px[k * THREADS + tid];
        hx[k] = t.x; hy[k] = t.y; hz[k] = t.z; hw[k] = t.w;
        mn = fminf(mn, fminf(fminf(t.x, t.y), fminf(t.z, t.w)));
        mx = fmaxf(mx, fmaxf(fmaxf(t.x, t.y), fmaxf(t.z, t.w)));
    }
    // OPAQUE PIN: provenance hidden -> compiler cannot re-load from global
    // in phase 2 (round-10 lesson: VGPR=64 proved silent rematerialization).
    #pragma unroll
    for (int k = 0; k < NREG; ++k)
        asm volatile("" : "+v"(hx[k]), "+v"(hy[k]), "+v"(hz[k]), "+v"(hw[k]));

    #pragma unroll
    for (int j = 0; j < NLDS; ++j) {
        const f32x4 t = px[(NREG + j) * THREADS + tid];
        mn = fminf(mn, fminf(fminf(t.x, t.y), fminf(t.z, t.w)));
        mx = fmaxf(mx, fmaxf(fmaxf(t.x, t.y), fmaxf(t.z, t.w)));
        slds[j * THREADS + tid] = t;   // own slot; no barrier needed
    }
    // unheld tail loaded LAST -> newest LRU lines when phase 2 begins
    #pragma unroll 8
    for (int j = 0; j < NUNH; ++j) {
        const f32x4 t = px[(NREG + NLDS + j) * THREADS + tid];
        mn = fminf(mn, fminf(fminf(t.x, t.y), fminf(t.z, t.w)));
        mx = fmaxf(mx, fmaxf(fmaxf(t.x, t.y), fmaxf(t.z, t.w)));
    }

    smn[tid] = mn; smx[tid] = mx;
    __syncthreads();
    for (int s = THREADS / 2; s > 0; s >>= 1) {
        if (tid < s) {
            smn[tid] = fminf(smn[tid], smn[tid + s]);
            smx[tid] = fmaxf(smx[tid], smx[tid + s]);
        }
        __syncthreads();
    }

    // ---- params (thread 0; block-local min/max, exact) ----
    if (tid == 0) {
        const float cmn = smn[0];
        const float cmx = smx[0];
        const float range = sub_rn(cmx, cmn);

        float pos[RNUM - 1];
        #pragma unroll
        for (int i = 0; i < RNUM - 1; ++i)
            pos[i] = add_rn(mul_rn(region_percentiles[chan * (RNUM - 1) + i], range), cmn);
        for (int i = 1; i < RNUM - 1; ++i) {   // insertion sort, 7 elems
            float v = pos[i];
            int j = i - 1;
            while (j >= 0 && pos[j] > v) { pos[j + 1] = pos[j]; --j; }
            pos[j + 1] = v;
        }
        #pragma unroll
        for (int i = 0; i < RNUM - 1; ++i) sprm[i] = pos[i];
        #pragma unroll
        for (int i = 0; i < RNUM; ++i) {
            const float left  = (i == 0)        ? cmn : pos[i - 1];
            const float right = (i == RNUM - 1) ? add_rn(cmx, 1e-6f) : pos[i];
            sprm[RNUM - 1 + i] = add_rn(left,
                                        mul_rn(proxy_percentiles[chan * RNUM + i],
                                               sub_rn(right, left)));
        }
    }
    __syncthreads();

    const float b0 = sprm[0], b1 = sprm[1], b2 = sprm[2], b3 = sprm[3];
    const float b4 = sprm[4], b5 = sprm[5], b6 = sprm[6];
    const float r0 = sprm[7],  r1 = sprm[8],  r2 = sprm[9],  r3 = sprm[10];
    const float r4 = sprm[11], r5 = sprm[12], r6 = sprm[13], r7 = sprm[14];

    // ---- phase 2: unheld first (L3-resident), then LDS, then registers ----
    #pragma unroll 8
    for (int j = 0; j < NUNH; ++j) {
        const int idx = (NREG + NLDS + j) * THREADS + tid;
        const f32x4 v = px[idx];
        f32x4 o;
        o.x = bst_sel(v.x, b0,b1,b2,b3,b4,b5,b6, r0,r1,r2,r3,r4,r5,r6,r7);
        o.y = bst_sel(v.y, b0,b1,b2,b3,b4,b5,b6, r0,r1,r2,r3,r4,r5,r6,r7);
        o.z = bst_sel(v.z, b0,b1,b2,b3,b4,b5,b6, r0,r1,r2,r3,r4,r5,r6,r7);
        o.w = bst_sel(v.w, b0,b1,b2,b3,b4,b5,b6, r0,r1,r2,r3,r4,r5,r6,r7);
        __builtin_nontemporal_store(o, &po[idx]);
    }
    #pragma unroll
    for (int j = 0; j < NLDS; ++j) {
        const f32x4 v = slds[j * THREADS + tid];
        f32x4 o;
        o.x = bst_sel(v.x, b0,b1,b2,b3,b4,b5,b6, r0,r1,r2,r3,r4,r5,r6,r7);
        o.y = bst_sel(v.y, b0,b1,b2,b3,b4,b5,b6, r0,r1,r2,r3,r4,r5,r6,r7);
        o.z = bst_sel(v.z, b0,b1,b2,b3,b4,b5,b6, r0,r1,r2,r3,r4,r5,r6,r7);
        o.w = bst_sel(v.w, b0,b1,b2,b3,b4,b5,b6, r0,r1,r2,r3,r4,r5,r6,r7);
        __builtin_nontemporal_store(o, &po[(NREG + j) * THREADS + tid]);
    }
    #pragma unroll
    for (int k = 0; k < NREG; ++k) {
        f32x4 o;
        o.x = bst_sel(hx[k], b0,b1,b2,b3,b4,b5,b6, r0,r1,r2,r3,r4,r5,r6,r7);
        o.y = bst_sel(hy[k], b0,b1,b2,b3,b4,b5,b6, r0,r1,r2,r3,r4,r5,r6,r7);
        o.z = bst_sel(hz[k], b0,b1,b2,b3,b4,b5,b6, r0,r1,r2,r3,r4,r5,r6,r7);
        o.w = bst_sel(hw[k], b0,b1,b2,b3,b4,b5,b6, r0,r1,r2,r3,r4,r5,r6,r7);
        __builtin_nontemporal_store(o, &po[k * THREADS + tid]);
    }
}

// ---------------------------------------------------------------------------
extern "C" void kernel_launch(void* const* d_in, const int* in_sizes, int n_in,
                              void* d_out, int out_size, void* d_ws, size_t ws_size,
                              hipStream_t stream) {
    const float* x  = (const float*)d_in[0];
    const float* rp = (const float*)d_in[1];
    const float* pp = (const float*)d_in[2];
    float* out = (float*)d_out;

    k_fused<<<CCH, THREADS, 0, stream>>>(x, rp, pp, out);
}

// Round 17
// 94.180 us; speedup vs baseline: 1.4225x; 1.4225x over previous
//
#include <hip/hip_runtime.h>
#include <math.h>

#pragma clang fp contract(off)

// Problem constants (fixed shapes from the reference)
#define CCH   192          // B*c = 64*3
#define HW    (512*512)    // 262144 pixels per channel
#define RNUM  8            // region_num
#define SPLIT 8            // blocks per channel, BOTH passes (same chunk map)

typedef float f32x4 __attribute__((ext_vector_type(4)));

// ---------------------------------------------------------------------------
// Un-contractible fp32 RN ops (HIP's __f*_rn are contractable; hipcc default
// -ffp-contract=fast-honor-pragmas fused mul+add in round 1 -> region flips).
// absmax==0.0 confirmed rounds 4-14 with these.
// ---------------------------------------------------------------------------
__device__ __forceinline__ float mul_rn(float a, float b) {
    float r; asm volatile("v_mul_f32 %0, %1, %2" : "=v"(r) : "v"(a), "v"(b)); return r;
}
__device__ __forceinline__ float add_rn(float a, float b) {
    float r; asm volatile("v_add_f32 %0, %1, %2" : "=v"(r) : "v"(a), "v"(b)); return r;
}
__device__ __forceinline__ float sub_rn(float a, float b) {
    float r; asm volatile("v_sub_f32 %0, %1, %2" : "=v"(r) : "v"(a), "v"(b)); return r;
}

#define N4_PER_BLOCK (HW / 4 / SPLIT)      // 8192 f32x4 per block
#define STEPS        (N4_PER_BLOCK / 256)  // 32 strided steps per thread

// ---------------------------------------------------------------------------
// Pass 1: per-(channel, split) min/max partial reduction. float4 loads,
// ASCENDING stride loop; at pass end each thread-chunk's LATE indices are
// the newest lines in L3 (sawtooth recency).
// ---------------------------------------------------------------------------
__global__ __launch_bounds__(256) void k_minmax(const float* __restrict__ x,
                                                float* __restrict__ ws) {
    __shared__ float smn[256], smx[256];
    const int chan = blockIdx.x / SPLIT;
    const int part = blockIdx.x % SPLIT;

    const f32x4* px = (const f32x4*)(x + (size_t)chan * HW) + (size_t)part * N4_PER_BLOCK;

    float mn = INFINITY, mx = -INFINITY;
    #pragma unroll 4
    for (int i = threadIdx.x; i < N4_PER_BLOCK; i += 256) {
        f32x4 v = px[i];
        mn = fminf(mn, fminf(fminf(v.x, v.y), fminf(v.z, v.w)));
        mx = fmaxf(mx, fmaxf(fmaxf(v.x, v.y), fmaxf(v.z, v.w)));
    }
    smn[threadIdx.x] = mn;
    smx[threadIdx.x] = mx;
    __syncthreads();
    for (int s = 128; s > 0; s >>= 1) {
        if (threadIdx.x < s) {
            smn[threadIdx.x] = fminf(smn[threadIdx.x], smn[threadIdx.x + s]);
            smx[threadIdx.x] = fmaxf(smx[threadIdx.x], smx[threadIdx.x + s]);
        }
        __syncthreads();
    }
    if (threadIdx.x == 0) {
        ws[(size_t)blockIdx.x * 2 + 0] = smn[0];
        ws[(size_t)blockIdx.x * 2 + 1] = smx[0];
    }
}

// ---------------------------------------------------------------------------
// Pass 2 (fused params+apply): same grid geometry/chunk map as pass 1, but
// each thread walks its chunk in REVERSE (newest-recency L3 lines first;
// LRU eviction by the write stream consumes the oldest lines, needed last).
// Per-pixel value via register BST (7 v_cmp + 7 v_cndmask, no per-elem LDS).
// NT stores keep the write stream from allocating in cache.
// ---------------------------------------------------------------------------
__global__ __launch_bounds__(256) void k_apply(const float* __restrict__ x,
                                               const float* __restrict__ ws_part,
                                               const float* __restrict__ region_percentiles,
                                               const float* __restrict__ proxy_percentiles,
                                               float* __restrict__ out) {
    const int chan = blockIdx.x / SPLIT;
    const int blk  = blockIdx.x % SPLIT;

    __shared__ float spart[2 * SPLIT];
    __shared__ float sb[RNUM - 1];
    __shared__ float srv[RNUM];

    if (threadIdx.x < 2 * SPLIT)
        spart[threadIdx.x] = ws_part[chan * 2 * SPLIT + threadIdx.x];
    __syncthreads();

    if (threadIdx.x == 0) {
        float mn = INFINITY, mx = -INFINITY;
        #pragma unroll
        for (int p = 0; p < SPLIT; ++p) {
            mn = fminf(mn, spart[2 * p + 0]);
            mx = fmaxf(mx, spart[2 * p + 1]);
        }
        const float range = sub_rn(mx, mn);

        float pos[RNUM - 1];
        #pragma unroll
        for (int i = 0; i < RNUM - 1; ++i)
            pos[i] = add_rn(mul_rn(region_percentiles[chan * (RNUM - 1) + i], range), mn);
        // insertion sort (7 elements)
        for (int i = 1; i < RNUM - 1; ++i) {
            float v = pos[i];
            int j = i - 1;
            while (j >= 0 && pos[j] > v) { pos[j + 1] = pos[j]; --j; }
            pos[j + 1] = v;
        }
        #pragma unroll
        for (int i = 0; i < RNUM - 1; ++i) sb[i] = pos[i];
        #pragma unroll
        for (int i = 0; i < RNUM; ++i) {
            const float left  = (i == 0)        ? mn : pos[i - 1];
            const float right = (i == RNUM - 1) ? add_rn(mx, 1e-6f) : pos[i];
            srv[i] = add_rn(left,
                            mul_rn(proxy_percentiles[chan * RNUM + i],
                                   sub_rn(right, left)));
        }
    }
    __syncthreads();

    // broadcast params into registers
    const float b0 = sb[0], b1 = sb[1], b2 = sb[2], b3 = sb[3];
    const float b4 = sb[4], b5 = sb[5], b6 = sb[6];
    const float r0 = srv[0], r1 = srv[1], r2 = srv[2], r3 = srv[3];
    const float r4 = srv[4], r5 = srv[5], r6 = srv[6], r7 = srv[7];

    const f32x4* px = (const f32x4*)(x   + (size_t)chan * HW) + (size_t)blk * N4_PER_BLOCK;
    f32x4*       po = (f32x4*)      (out + (size_t)chan * HW) + (size_t)blk * N4_PER_BLOCK;

    // REVERSE walk of the exact index set pass 1 touched (newest lines first)
    #pragma unroll 4
    for (int i = (STEPS - 1) * 256 + (int)threadIdx.x; i >= 0; i -= 256) {
        const f32x4 v = px[i];
        f32x4 o;
        o.x = (v.x < b3) ? ((v.x < b1) ? ((v.x < b0) ? r0 : r1)
                                       : ((v.x < b2) ? r2 : r3))
                         : ((v.x < b5) ? ((v.x < b4) ? r4 : r5)
                                       : ((v.x < b6) ? r6 : r7));
        o.y = (v.y < b3) ? ((v.y < b1) ? ((v.y < b0) ? r0 : r1)
                                       : ((v.y < b2) ? r2 : r3))
                         : ((v.y < b5) ? ((v.y < b4) ? r4 : r5)
                                       : ((v.y < b6) ? r6 : r7));
        o.z = (v.z < b3) ? ((v.z < b1) ? ((v.z < b0) ? r0 : r1)
                                       : ((v.z < b2) ? r2 : r3))
                         : ((v.z < b5) ? ((v.z < b4) ? r4 : r5)
                                       : ((v.z < b6) ? r6 : r7));
        o.w = (v.w < b3) ? ((v.w < b1) ? ((v.w < b0) ? r0 : r1)
                                       : ((v.w < b2) ? r2 : r3))
                         : ((v.w < b5) ? ((v.w < b4) ? r4 : r5)
                                       : ((v.w < b6) ? r6 : r7));
        __builtin_nontemporal_store(o, &po[i]);
    }
}

// ---------------------------------------------------------------------------
extern "C" void kernel_launch(void* const* d_in, const int* in_sizes, int n_in,
                              void* d_out, int out_size, void* d_ws, size_t ws_size,
                              hipStream_t stream) {
    const float* x  = (const float*)d_in[0];
    const float* rp = (const float*)d_in[1];  // region_percentiles, C*(R-1)
    const float* pp = (const float*)d_in[2];  // proxy_percentiles,  C*R
    // d_in[3] = region_num (hard-coded 8, matches reference constant)
    float* out = (float*)d_out;
    float* ws  = (float*)d_ws;

    k_minmax<<<CCH * SPLIT, 256, 0, stream>>>(x, ws);
    k_apply<<<CCH * SPLIT, 256, 0, stream>>>(x, ws, rp, pp, out);
}